// Round 3
// baseline (401.684 us; speedup 1.0000x reference)
//
#include <hip/hip_runtime.h>
#include <hip/hip_bf16.h>

typedef __bf16 bf16x8 __attribute__((ext_vector_type(8)));
typedef float f32x4 __attribute__((ext_vector_type(4)));
typedef unsigned short u16;

#define S_ 2048
#define D_ 2048
#define H_ 16
#define HD_ 128
#define SCALE_ 0.08838834764831845f   // 1/sqrt(128)

__device__ __forceinline__ u16 f2bf(float f) {
  unsigned u = __builtin_bit_cast(unsigned, f);
  u += 0x7fffu + ((u >> 16) & 1u);    // RNE
  return (u16)(u >> 16);
}

__device__ __forceinline__ void gload16(void* lds, const void* g) {
  __builtin_amdgcn_global_load_lds((const __attribute__((address_space(1))) void*)g,
                                   (__attribute__((address_space(3))) void*)lds, 16, 0, 0);
}

__device__ __forceinline__ f32x4 mfma16(bf16x8 a, bf16x8 b, f32x4 c) {
  return __builtin_amdgcn_mfma_f32_16x16x32_bf16(a, b, c, 0, 0, 0);
}

// ---------------- cast f32 -> bf16, vectorized ----------------
__global__ void k_cast_bf16(const float* __restrict__ in, u16* __restrict__ out, int n4) {
  int i = blockIdx.x * blockDim.x + threadIdx.x;
  if (i < n4) {
    float4 v = ((const float4*)in)[i];
    ushort4 o;
    o.x = f2bf(v.x); o.y = f2bf(v.y); o.z = f2bf(v.z); o.w = f2bf(v.w);
    ((ushort4*)out)[i] = o;
  }
}

// ------------- transpose + cast: in[rows][cols] f32 -> out[cols][rows] bf16 -------------
__global__ void k_transpose_cast(const float* __restrict__ in, u16* __restrict__ out,
                                 int rows, int cols) {
  __shared__ u16 tile[32][33];
  int c0 = blockIdx.x * 32, r0 = blockIdx.y * 32;
  int tx = threadIdx.x, ty = threadIdx.y;   // (32,8)
#pragma unroll
  for (int i = 0; i < 4; i++) {
    int r = r0 + ty + i * 8;
    tile[ty + i * 8][tx] = f2bf(in[(long)r * cols + c0 + tx]);
  }
  __syncthreads();
#pragma unroll
  for (int i = 0; i < 4; i++) {
    int c = c0 + ty + i * 8;
    out[(long)c * rows + r0 + tx] = tile[tx][ty + i * 8];
  }
}

// ------------- extract V^T: qkv[4096][6144] -> vt[32][128][2048] -------------
__global__ void k_extract_vt(const u16* __restrict__ qkv, u16* __restrict__ vt) {
  __shared__ u16 tile[32][33];
  int bh = blockIdx.z, b = bh >> 4, h = bh & 15;
  int d0 = blockIdx.x * 32, s0 = blockIdx.y * 32;
  int tx = threadIdx.x, ty = threadIdx.y;
#pragma unroll
  for (int i = 0; i < 4; i++) {
    int s = s0 + ty + i * 8;
    tile[ty + i * 8][tx] = qkv[(long)(b * S_ + s) * 6144 + h * 384 + 256 + d0 + tx];
  }
  __syncthreads();
#pragma unroll
  for (int i = 0; i < 4; i++) {
    int d = d0 + ty + i * 8;
    vt[((long)bh * HD_ + d) * S_ + s0 + tx] = tile[tx][ty + i * 8];
  }
}

// ------------- GEMM: C[M][N] = A[M][K] * Bt[N][K]^T + bias, A/Bt bf16, acc f32 -------------
// 128x128 tile, 4 waves (2x2 of 64x64), BK=32, global_load_lds staging, XOR-swizzled LDS.
template <bool BF16OUT>
__global__ __launch_bounds__(256) void k_gemm_bt(const u16* __restrict__ A,
                                                 const u16* __restrict__ Bt,
                                                 const float* __restrict__ bias,
                                                 void* __restrict__ Cv,
                                                 int M, int N, int K) {
  __shared__ u16 lA[128 * 32];
  __shared__ u16 lB[128 * 32];
  const int tid = threadIdx.x;
  const int w = tid >> 6, l = tid & 63;
  const int wr = w >> 1, wc = w & 1;
  const int lr = l & 15, lg = l >> 4;
  const int tm = blockIdx.y * 128, tn = blockIdx.x * 128;
  const int Rr = l >> 2, Pp = l & 3;

  f32x4 acc[4][4];
#pragma unroll
  for (int m = 0; m < 4; m++)
#pragma unroll
    for (int n = 0; n < 4; n++) acc[m][n] = {0.f, 0.f, 0.f, 0.f};

  for (int k0 = 0; k0 < K; k0 += 32) {
#pragma unroll
    for (int i = 0; i < 2; i++) {
      int R = (i * 4 + w) * 16 + Rr;
      int cg = Pp ^ (R & 3);
      gload16(&lA[(i * 4 + w) * 512], &A[(long)(tm + R) * K + k0 + cg * 8]);
    }
#pragma unroll
    for (int i = 0; i < 2; i++) {
      int R = (i * 4 + w) * 16 + Rr;
      int cg = Pp ^ (R & 3);
      gload16(&lB[(i * 4 + w) * 512], &Bt[(long)(tn + R) * K + k0 + cg * 8]);
    }
    __syncthreads();
    bf16x8 af[4], bfr[4];
#pragma unroll
    for (int m = 0; m < 4; m++) {
      int r = wr * 64 + m * 16 + lr;
      af[m] = *(const bf16x8*)&lA[r * 32 + ((lg ^ (r & 3)) << 3)];
    }
#pragma unroll
    for (int n = 0; n < 4; n++) {
      int r = wc * 64 + n * 16 + lr;
      bfr[n] = *(const bf16x8*)&lB[r * 32 + ((lg ^ (r & 3)) << 3)];
    }
#pragma unroll
    for (int m = 0; m < 4; m++)
#pragma unroll
      for (int n = 0; n < 4; n++) acc[m][n] = mfma16(af[m], bfr[n], acc[m][n]);
    __syncthreads();
  }

#pragma unroll
  for (int n = 0; n < 4; n++) {
    int col = tn + wc * 64 + n * 16 + lr;
    float bv = bias[col];
#pragma unroll
    for (int m = 0; m < 4; m++) {
      int row0 = tm + wr * 64 + m * 16 + lg * 4;
#pragma unroll
      for (int j = 0; j < 4; j++) {
        float v = acc[m][n][j] + bv;
        if constexpr (BF16OUT)
          ((u16*)Cv)[(long)(row0 + j) * N + col] = f2bf(v);
        else
          ((float*)Cv)[(long)(row0 + j) * N + col] = v;
      }
    }
  }
}

// ------------- causal flash attention -------------
// grid (bh=32, y=16). qt remapped heavy-first: y<8 -> 15-y, else y-8 (LPT scheduling:
// the 32-tile blocks dispatch first, light blocks backfill -> no straggler tail).
// XCD = bh%8: each XCD serves 4 heads (4 MB K/V == its L2).
// 256 thr = 4 waves, each wave owns 32 q-rows. KV tiles of 64, double-buffered LDS
// with global_load_lds prefetch of tile t+1 issued before compute of tile t.
// Online softmax with defer-max (T13, THR=8): rescale only when row-max grows > 8.
__global__ __launch_bounds__(256) void k_attn(const u16* __restrict__ qkv,
                                              const u16* __restrict__ vt,
                                              const float* __restrict__ amask,
                                              u16* __restrict__ ctx) {
  __shared__ u16 lK[2][64 * 128];    // [key][d], chunk^(key&7) swizzle
  __shared__ u16 lV[2][128 * 64];    // [d][key], chunk^(d&7) swizzle
  __shared__ u16 lP[4][32 * 64];     // per-wave [qrow][key], chunk^(row&7) swizzle
  const int bh = blockIdx.x, b = bh >> 4, h = bh & 15;
  const int y = blockIdx.y;
  const int qt = (y < 8) ? (15 - y) : (y - 8);
  const int tid = threadIdx.x, w = tid >> 6, l = tid & 63;
  const int lr = l & 15, lg = l >> 4;
  const int qrow0 = qt * 128 + w * 32;

  // Q fragments held in registers (direct global loads, 16B aligned)
  bf16x8 qf[2][4];
#pragma unroll
  for (int m = 0; m < 2; m++)
#pragma unroll
    for (int ks = 0; ks < 4; ks++)
      qf[m][ks] = *(const bf16x8*)&qkv[(long)(b * S_ + qrow0 + m * 16 + lr) * 6144 +
                                       h * 384 + ks * 32 + lg * 8];

  f32x4 accO[2][8];
#pragma unroll
  for (int m = 0; m < 2; m++)
#pragma unroll
    for (int n = 0; n < 8; n++) accO[m][n] = {0.f, 0.f, 0.f, 0.f};
  float mrun[2][4], lrun[2][4];
#pragma unroll
  for (int m = 0; m < 2; m++)
#pragma unroll
    for (int j = 0; j < 4; j++) { mrun[m][j] = -3.0e38f; lrun[m][j] = 0.f; }

  const int ntiles = 2 * qt + 2;

  // staging helper: K tile [64][128] + Vt tile [128][64] into buffer `buf`
  auto stage = [&](int buf, int t) {
#pragma unroll
    for (int i = 0; i < 4; i++) {
      int base = i * 256 + w * 64;             // wave-uniform chunk base
      int f = base + l;
      int r = f >> 4, cg = (f & 15) ^ (r & 7);
      gload16(&lK[buf][base * 8],
              &qkv[(long)(b * S_ + t * 64 + r) * 6144 + h * 384 + 128 + cg * 8]);
    }
#pragma unroll
    for (int i = 0; i < 4; i++) {
      int base = i * 256 + w * 64;
      int f = base + l;
      int r = f >> 3, cg = (f & 7) ^ (r & 7);
      gload16(&lV[buf][base * 8], &vt[((long)bh * HD_ + r) * S_ + t * 64 + cg * 8]);
    }
  };

  stage(0, 0);
  __syncthreads();

  for (int t = 0; t < ntiles; ++t) {
    const int cur = t & 1;
    if (t + 1 < ntiles) stage(cur ^ 1, t + 1);   // prefetch next tile (overlaps compute)

    const bool active = (t * 64 <= qrow0 + 31);
    if (active) {
      // QK^T
      f32x4 accS[2][4];
#pragma unroll
      for (int m = 0; m < 2; m++)
#pragma unroll
        for (int n = 0; n < 4; n++) accS[m][n] = {0.f, 0.f, 0.f, 0.f};
      __builtin_amdgcn_s_setprio(1);
#pragma unroll
      for (int ks = 0; ks < 4; ks++) {
        bf16x8 kf[4];
#pragma unroll
        for (int n = 0; n < 4; n++) {
          int key = n * 16 + lr;
          kf[n] = *(const bf16x8*)&lK[cur][key * 128 + (((ks * 4 + lg) ^ (key & 7)) << 3)];
        }
#pragma unroll
        for (int m = 0; m < 2; m++)
#pragma unroll
          for (int n = 0; n < 4; n++) accS[m][n] = mfma16(qf[m][ks], kf[n], accS[m][n]);
      }
      __builtin_amdgcn_s_setprio(0);
      float am[4];
#pragma unroll
      for (int n = 0; n < 4; n++) am[n] = amask[b * S_ + t * 64 + n * 16 + lr];
      const bool needmask = (t * 64 + 63 > qrow0);
      // online softmax per owned row (m,j); 4 rows in parallel across lg groups
#pragma unroll
      for (int m = 0; m < 2; m++) {
#pragma unroll
        for (int j = 0; j < 4; j++) {
          const int row = qrow0 + m * 16 + lg * 4 + j;
          const int prow = m * 16 + lg * 4 + j;
          float v[4];
#pragma unroll
          for (int n = 0; n < 4; n++) {
            v[n] = accS[m][n][j] * SCALE_ + am[n];
            if (needmask && (t * 64 + n * 16 + lr) > row) v[n] = -1e30f;
          }
          float rmax = fmaxf(fmaxf(v[0], v[1]), fmaxf(v[2], v[3]));
#pragma unroll
          for (int o = 1; o < 16; o <<= 1) rmax = fmaxf(rmax, __shfl_xor(rmax, o));
          // defer-max: only rescale when the row max grew by > 8 (uniform per 16-group)
          if (rmax > mrun[m][j] + 8.0f) {
            const float corr = __expf(mrun[m][j] - rmax);
            lrun[m][j] *= corr;
            mrun[m][j] = rmax;
#pragma unroll
            for (int n = 0; n < 8; n++) accO[m][n][j] *= corr;
          }
          float ls = 0.f;
#pragma unroll
          for (int n = 0; n < 4; n++) {
            float p = __expf(v[n] - mrun[m][j]);
            ls += p;
            int pcol = n * 16 + lr;
            lP[w][prow * 64 + ((((pcol >> 3) ^ (prow & 7)) << 3) | (pcol & 7))] = f2bf(p);
          }
#pragma unroll
          for (int o = 1; o < 16; o <<= 1) ls += __shfl_xor(ls, o);
          lrun[m][j] += ls;
        }
      }
      // PV: O += P * V   (A = P from wave-private LDS, B^T = Vt)
      __builtin_amdgcn_s_setprio(1);
#pragma unroll
      for (int ks = 0; ks < 2; ks++) {
        bf16x8 pa[2];
#pragma unroll
        for (int m = 0; m < 2; m++) {
          int r = m * 16 + lr;
          pa[m] = *(const bf16x8*)&lP[w][r * 64 + (((ks * 4 + lg) ^ (r & 7)) << 3)];
        }
#pragma unroll
        for (int n = 0; n < 8; n++) {
          int d = n * 16 + lr;
          bf16x8 vb = *(const bf16x8*)&lV[cur][d * 64 + (((ks * 4 + lg) ^ (d & 7)) << 3)];
#pragma unroll
          for (int m = 0; m < 2; m++) accO[m][n] = mfma16(pa[m], vb, accO[m][n]);
        }
      }
      __builtin_amdgcn_s_setprio(0);
    }
    __syncthreads();   // drains prefetch vmcnt (overlapped with compute) + LDS reads
  }

  // epilogue: O /= l, write ctx[b,s, h*128 + d] bf16
#pragma unroll
  for (int m = 0; m < 2; m++) {
#pragma unroll
    for (int j = 0; j < 4; j++) {
      float inv = 1.0f / lrun[m][j];
      int srow = qrow0 + m * 16 + lg * 4 + j;
#pragma unroll
      for (int n = 0; n < 8; n++)
        ctx[(long)(b * S_ + srow) * D_ + h * HD_ + n * 16 + lr] = f2bf(accO[m][n][j] * inv);
    }
  }
}

extern "C" void kernel_launch(void* const* d_in, const int* in_sizes, int n_in,
                              void* d_out, int out_size, void* d_ws, size_t ws_size,
                              hipStream_t stream) {
  const float* x  = (const float*)d_in[0];
  const float* am = (const float*)d_in[1];
  const float* wq = (const float*)d_in[2];
  const float* bq = (const float*)d_in[3];
  const float* wd = (const float*)d_in[4];
  const float* bd = (const float*)d_in[5];
  float* out = (float*)d_out;
  char* ws = (char*)d_ws;

  // workspace layout (92.3 MB peak, overlaid):
  u16* xb   = (u16*)(ws);                          // [4096][2048] bf16, 16 MB
  u16* wqT  = (u16*)(ws + (size_t)16777216);       // [6144][2048] bf16, 24 MB
  u16* qkvb = (u16*)(ws + (size_t)41943040);       // [4096][6144] bf16, 48 MB
  u16* vtb  = (u16*)(ws + (size_t)16777216);       // [32][128][2048] bf16 (reuses wqT)
  u16* wdT  = (u16*)(ws + (size_t)33554432);       // [2048][2048] bf16 (reuses wqT tail)
  u16* ctxb = (u16*)(ws);                          // [4096][2048] bf16 (reuses xb)

  k_cast_bf16<<<8192, 256, 0, stream>>>(x, xb, 2097152);
  k_transpose_cast<<<dim3(192, 64), dim3(32, 8), 0, stream>>>(wq, wqT, 2048, 6144);
  k_gemm_bt<true><<<dim3(48, 32), 256, 0, stream>>>(xb, wqT, bq, (void*)qkvb, 4096, 6144, 2048);
  k_extract_vt<<<dim3(4, 64, 32), dim3(32, 8), 0, stream>>>(qkvb, vtb);
  k_transpose_cast<<<dim3(64, 64), dim3(32, 8), 0, stream>>>(wd, wdT, 2048, 2048);
  k_attn<<<dim3(32, 16), 256, 0, stream>>>(qkvb, vtb, am, ctxb);
  k_gemm_bt<false><<<dim3(16, 32), 256, 0, stream>>>(ctxb, wdT, bd, (void*)out, 4096, 2048, 2048);
}

// Round 4
// 349.055 us; speedup vs baseline: 1.1508x; 1.1508x over previous
//
#include <hip/hip_runtime.h>
#include <hip/hip_bf16.h>

typedef __bf16 bf16x8 __attribute__((ext_vector_type(8)));
typedef float f32x4 __attribute__((ext_vector_type(4)));
typedef float f32x16 __attribute__((ext_vector_type(16)));
typedef unsigned short u16;

#define S_ 2048
#define D_ 2048
#define H_ 16
#define HD_ 128
#define SCALE_ 0.08838834764831845f   // 1/sqrt(128)

__device__ __forceinline__ u16 f2bf(float f) {
  unsigned u = __builtin_bit_cast(unsigned, f);
  u += 0x7fffu + ((u >> 16) & 1u);    // RNE
  return (u16)(u >> 16);
}

__device__ __forceinline__ void gload16(void* lds, const void* g) {
  __builtin_amdgcn_global_load_lds((const __attribute__((address_space(1))) void*)g,
                                   (__attribute__((address_space(3))) void*)lds, 16, 0, 0);
}

__device__ __forceinline__ f32x4 mfma16(bf16x8 a, bf16x8 b, f32x4 c) {
  return __builtin_amdgcn_mfma_f32_16x16x32_bf16(a, b, c, 0, 0, 0);
}
__device__ __forceinline__ f32x16 mfma32(bf16x8 a, bf16x8 b, f32x16 c) {
  return __builtin_amdgcn_mfma_f32_32x32x16_bf16(a, b, c, 0, 0, 0);
}

__device__ __forceinline__ unsigned cvt_pk_bf16(float lo, float hi) {
  unsigned r;
  asm("v_cvt_pk_bf16_f32 %0, %1, %2" : "=v"(r) : "v"(lo), "v"(hi));
  return r;
}

// ---------------- cast f32 -> bf16, vectorized ----------------
__global__ void k_cast_bf16(const float* __restrict__ in, u16* __restrict__ out, int n4) {
  int i = blockIdx.x * blockDim.x + threadIdx.x;
  if (i < n4) {
    float4 v = ((const float4*)in)[i];
    ushort4 o;
    o.x = f2bf(v.x); o.y = f2bf(v.y); o.z = f2bf(v.z); o.w = f2bf(v.w);
    ((ushort4*)out)[i] = o;
  }
}

// ------------- transpose + cast: in[rows][cols] f32 -> out[cols][rows] bf16 -------------
__global__ void k_transpose_cast(const float* __restrict__ in, u16* __restrict__ out,
                                 int rows, int cols) {
  __shared__ u16 tile[32][33];
  int c0 = blockIdx.x * 32, r0 = blockIdx.y * 32;
  int tx = threadIdx.x, ty = threadIdx.y;   // (32,8)
#pragma unroll
  for (int i = 0; i < 4; i++) {
    int r = r0 + ty + i * 8;
    tile[ty + i * 8][tx] = f2bf(in[(long)r * cols + c0 + tx]);
  }
  __syncthreads();
#pragma unroll
  for (int i = 0; i < 4; i++) {
    int c = c0 + ty + i * 8;
    out[(long)c * rows + r0 + tx] = tile[tx][ty + i * 8];
  }
}

// ------------- extract V^T: qkv[4096][6144] -> vt[32][128][2048] -------------
__global__ void k_extract_vt(const u16* __restrict__ qkv, u16* __restrict__ vt) {
  __shared__ u16 tile[32][33];
  int bh = blockIdx.z, b = bh >> 4, h = bh & 15;
  int d0 = blockIdx.x * 32, s0 = blockIdx.y * 32;
  int tx = threadIdx.x, ty = threadIdx.y;
#pragma unroll
  for (int i = 0; i < 4; i++) {
    int s = s0 + ty + i * 8;
    tile[ty + i * 8][tx] = qkv[(long)(b * S_ + s) * 6144 + h * 384 + 256 + d0 + tx];
  }
  __syncthreads();
#pragma unroll
  for (int i = 0; i < 4; i++) {
    int d = d0 + ty + i * 8;
    vt[((long)bh * HD_ + d) * S_ + s0 + tx] = tile[tx][ty + i * 8];
  }
}

// ------------- GEMM: C[M][N] = A[M][K] * Bt[N][K]^T + bias, A/Bt bf16, acc f32 -------------
template <bool BF16OUT>
__global__ __launch_bounds__(256) void k_gemm_bt(const u16* __restrict__ A,
                                                 const u16* __restrict__ Bt,
                                                 const float* __restrict__ bias,
                                                 void* __restrict__ Cv,
                                                 int M, int N, int K) {
  __shared__ u16 lA[128 * 32];
  __shared__ u16 lB[128 * 32];
  const int tid = threadIdx.x;
  const int w = tid >> 6, l = tid & 63;
  const int wr = w >> 1, wc = w & 1;
  const int lr = l & 15, lg = l >> 4;
  const int tm = blockIdx.y * 128, tn = blockIdx.x * 128;
  const int Rr = l >> 2, Pp = l & 3;

  f32x4 acc[4][4];
#pragma unroll
  for (int m = 0; m < 4; m++)
#pragma unroll
    for (int n = 0; n < 4; n++) acc[m][n] = {0.f, 0.f, 0.f, 0.f};

  for (int k0 = 0; k0 < K; k0 += 32) {
#pragma unroll
    for (int i = 0; i < 2; i++) {
      int R = (i * 4 + w) * 16 + Rr;
      int cg = Pp ^ (R & 3);
      gload16(&lA[(i * 4 + w) * 512], &A[(long)(tm + R) * K + k0 + cg * 8]);
    }
#pragma unroll
    for (int i = 0; i < 2; i++) {
      int R = (i * 4 + w) * 16 + Rr;
      int cg = Pp ^ (R & 3);
      gload16(&lB[(i * 4 + w) * 512], &Bt[(long)(tn + R) * K + k0 + cg * 8]);
    }
    __syncthreads();
    bf16x8 af[4], bfr[4];
#pragma unroll
    for (int m = 0; m < 4; m++) {
      int r = wr * 64 + m * 16 + lr;
      af[m] = *(const bf16x8*)&lA[r * 32 + ((lg ^ (r & 3)) << 3)];
    }
#pragma unroll
    for (int n = 0; n < 4; n++) {
      int r = wc * 64 + n * 16 + lr;
      bfr[n] = *(const bf16x8*)&lB[r * 32 + ((lg ^ (r & 3)) << 3)];
    }
#pragma unroll
    for (int m = 0; m < 4; m++)
#pragma unroll
      for (int n = 0; n < 4; n++) acc[m][n] = mfma16(af[m], bfr[n], acc[m][n]);
    __syncthreads();
  }

#pragma unroll
  for (int n = 0; n < 4; n++) {
    int col = tn + wc * 64 + n * 16 + lr;
    float bv = bias[col];
#pragma unroll
    for (int m = 0; m < 4; m++) {
      int row0 = tm + wr * 64 + m * 16 + lg * 4;
#pragma unroll
      for (int j = 0; j < 4; j++) {
        float v = acc[m][n][j] + bv;
        if constexpr (BF16OUT)
          ((u16*)Cv)[(long)(row0 + j) * N + col] = f2bf(v);
        else
          ((float*)Cv)[(long)(row0 + j) * N + col] = v;
      }
    }
  }
}

// ------------- causal flash attention, 32x32 swapped-MFMA form -------------
// grid (bh=32, c=16). Block = 4 waves x 32 q-rows covering chunk pair (c, 31-c):
// waves 0,1 -> rows [c*64, c*64+64); waves 2,3 -> rows [(31-c)*64, ...). Every block
// does exactly 66 wave-tile computes -> balanced at any dispatch order.
// Swapped QK' = mfma32(K,Q) -> S'[key][qrow], qrow = lane&31 (lane-local row stats).
// P kept in registers: cvt_pk pairs + shfl_xor(32) exchange -> PV A-fragments.
// LDS: K/V double-buffered (64 KB) + amask tile (8 KB) = 72 KB -> 2 blocks/CU.
__global__ __launch_bounds__(256) void k_attn(const u16* __restrict__ qkv,
                                              const u16* __restrict__ vt,
                                              const float* __restrict__ amask,
                                              u16* __restrict__ ctx) {
  __shared__ u16 lK[2][64 * 128];    // [key][d], 16B-chunk ^(key&7) swizzle
  __shared__ u16 lV[2][128 * 64];    // [d][key], 16B-chunk ^(d&7) swizzle
  __shared__ float lAM[S_];          // amask row for this b
  const int bh = blockIdx.x, b = bh >> 4, h = bh & 15;
  const int c = blockIdx.y;
  const int tid = threadIdx.x, w = tid >> 6, l = tid & 63;
  const int lr5 = l & 31, hi = l >> 5;
  const int qrow0 = (w < 2) ? (c * 64 + w * 32) : ((31 - c) * 64 + (w - 2) * 32);
  const int ntiles = 32 - c;

  // amask preload (per-b row of 2048 floats)
  for (int i = tid; i < S_; i += 256) lAM[i] = amask[b * S_ + i];

  // Q fragments: qf[ks] = Q[qrow0+lr5][ks*16 + hi*8 + 0..7]
  bf16x8 qf[8];
#pragma unroll
  for (int ks = 0; ks < 8; ks++)
    qf[ks] = *(const bf16x8*)&qkv[(long)(b * S_ + qrow0 + lr5) * 6144 +
                                  h * 384 + ks * 16 + hi * 8];

  f32x16 aO[4];
#pragma unroll
  for (int db = 0; db < 4; db++)
#pragma unroll
    for (int r = 0; r < 16; r++) aO[db][r] = 0.f;
  float mrun = -3.0e38f, lrun = 0.f;

  // staging: K tile [64][128] + Vt tile [128][64]
  auto stage = [&](int buf, int t) {
#pragma unroll
    for (int i = 0; i < 4; i++) {
      int base = i * 256 + w * 64;
      int f = base + l;
      int r = f >> 4, cg = (f & 15) ^ (r & 7);
      gload16(&lK[buf][base * 8],
              &qkv[(long)(b * S_ + t * 64 + r) * 6144 + h * 384 + 128 + cg * 8]);
    }
#pragma unroll
    for (int i = 0; i < 4; i++) {
      int base = i * 256 + w * 64;
      int f = base + l;
      int r = f >> 3, cg = (f & 7) ^ (r & 7);
      gload16(&lV[buf][base * 8], &vt[((long)bh * HD_ + r) * S_ + t * 64 + cg * 8]);
    }
  };

  stage(0, 0);
  __syncthreads();

  for (int t = 0; t < ntiles; ++t) {
    const int cur = t & 1;
    if (t + 1 < ntiles) stage(cur ^ 1, t + 1);   // prefetch overlaps compute

    if (t * 64 <= qrow0 + 31) {
      const int t64 = t * 64;
      const int qr = qrow0 + lr5;
      // ---- QK': S'[key][qrow] ----
      f32x16 aS0, aS1;
#pragma unroll
      for (int r = 0; r < 16; r++) { aS0[r] = 0.f; aS1[r] = 0.f; }
      __builtin_amdgcn_s_setprio(1);
#pragma unroll
      for (int ks = 0; ks < 8; ks++) {
        int cg = 2 * ks + hi;
        bf16x8 kf0 = *(const bf16x8*)&lK[cur][lr5 * 128 + ((cg ^ (lr5 & 7)) << 3)];
        bf16x8 kf1 = *(const bf16x8*)&lK[cur][(32 + lr5) * 128 + ((cg ^ (lr5 & 7)) << 3)];
        aS0 = mfma32(kf0, qf[ks], aS0);
        aS1 = mfma32(kf1, qf[ks], aS1);
      }
      __builtin_amdgcn_s_setprio(0);

      // ---- softmax (row = qr, lane-local) ----
      // value reg: key = kb*32 + j + 8*rg + 4*hi  (reg = rg*4+j)
      float v0[16], v1[16];
      const bool needmask = (t64 + 63 > qrow0);
#pragma unroll
      for (int rg = 0; rg < 4; rg++) {
        f32x4 am0 = *(const f32x4*)&lAM[t64 + rg * 8 + hi * 4];
        f32x4 am1 = *(const f32x4*)&lAM[t64 + 32 + rg * 8 + hi * 4];
#pragma unroll
        for (int j = 0; j < 4; j++) {
          v0[rg * 4 + j] = fmaf(aS0[rg * 4 + j], SCALE_, am0[j]);
          v1[rg * 4 + j] = fmaf(aS1[rg * 4 + j], SCALE_, am1[j]);
          if (needmask) {
            if (t64 + rg * 8 + 4 * hi + j > qr)      v0[rg * 4 + j] = -1e30f;
            if (t64 + 32 + rg * 8 + 4 * hi + j > qr) v1[rg * 4 + j] = -1e30f;
          }
        }
      }
      float mx = v0[0];
#pragma unroll
      for (int i = 1; i < 16; i++) mx = fmaxf(mx, v0[i]);
#pragma unroll
      for (int i = 0; i < 16; i++) mx = fmaxf(mx, v1[i]);
      mx = fmaxf(mx, __shfl_xor(mx, 32));

      // defer-max: wave-uniform skip of the rescale (T13)
      if (!__all(mx <= mrun + 8.0f)) {
        float mnew = fmaxf(mrun, mx);
        float corr = __expf(mrun - mnew);
        lrun *= corr;
        mrun = mnew;
#pragma unroll
        for (int reg = 0; reg < 16; reg++) {
          float cb = __shfl(corr, (reg & 3) + 8 * (reg >> 2) + 4 * hi);
#pragma unroll
          for (int db = 0; db < 4; db++) aO[db][reg] *= cb;
        }
      }

      float p0[16], p1[16], ls = 0.f;
#pragma unroll
      for (int i = 0; i < 16; i++) { p0[i] = __expf(v0[i] - mrun); ls += p0[i]; }
#pragma unroll
      for (int i = 0; i < 16; i++) { p1[i] = __expf(v1[i] - mrun); ls += p1[i]; }
      ls += __shfl_xor(ls, 32);
      lrun += ls;

      // ---- pack P -> bf16 pairs, exchange halves, build PV A-frags ----
      unsigned pk0[8], pk1[8];
#pragma unroll
      for (int q = 0; q < 8; q++) {
        pk0[q] = cvt_pk_bf16(p0[2 * q], p0[2 * q + 1]);
        pk1[q] = cvt_pk_bf16(p1[2 * q], p1[2 * q + 1]);
      }
      bf16x8 pa[4];
#pragma unroll
      for (int kst = 0; kst < 4; kst++) {
        const int j4 = kst & 1;
        unsigned a0, a1, a2, a3;
        if (kst < 2) { a0 = pk0[4 * j4]; a1 = pk0[4 * j4 + 1]; a2 = pk0[4 * j4 + 2]; a3 = pk0[4 * j4 + 3]; }
        else         { a0 = pk1[4 * j4]; a1 = pk1[4 * j4 + 1]; a2 = pk1[4 * j4 + 2]; a3 = pk1[4 * j4 + 3]; }
        unsigned s0 = hi ? a0 : a2;          // value my partner needs (c=0)
        unsigned s1 = hi ? a1 : a3;          // (c=1)
        unsigned r0 = __shfl_xor(s0, 32);
        unsigned r1 = __shfl_xor(s1, 32);
        union { unsigned u[4]; bf16x8 v; } U;
        U.u[0] = hi ? r0 : a0;
        U.u[1] = hi ? r1 : a1;
        U.u[2] = hi ? a2 : r0;
        U.u[3] = hi ? a3 : r1;
        pa[kst] = U.v;
      }

      // ---- PV: O[qrow][d] += P * V ----
      __builtin_amdgcn_s_setprio(1);
#pragma unroll
      for (int kst = 0; kst < 4; kst++) {
#pragma unroll
        for (int db = 0; db < 4; db++) {
          int d = db * 32 + lr5;
          int cg = (2 * kst + hi) ^ (d & 7);
          bf16x8 vb = *(const bf16x8*)&lV[cur][d * 64 + (cg << 3)];
          aO[db] = mfma32(pa[kst], vb, aO[db]);
        }
      }
      __builtin_amdgcn_s_setprio(0);
    }
    __syncthreads();
  }

  // epilogue: O /= lrun; write ctx[b, qrow, h*128 + d]
  float inv = 1.0f / lrun;
#pragma unroll
  for (int reg = 0; reg < 16; reg++) {
    int r = (reg & 3) + 8 * (reg >> 2) + 4 * hi;
    float ib = __shfl(inv, r);
    int srow = qrow0 + r;
#pragma unroll
    for (int db = 0; db < 4; db++)
      ctx[(long)(b * S_ + srow) * D_ + h * HD_ + db * 32 + lr5] = f2bf(aO[db][reg] * ib);
  }
}

extern "C" void kernel_launch(void* const* d_in, const int* in_sizes, int n_in,
                              void* d_out, int out_size, void* d_ws, size_t ws_size,
                              hipStream_t stream) {
  const float* x  = (const float*)d_in[0];
  const float* am = (const float*)d_in[1];
  const float* wq = (const float*)d_in[2];
  const float* bq = (const float*)d_in[3];
  const float* wd = (const float*)d_in[4];
  const float* bd = (const float*)d_in[5];
  float* out = (float*)d_out;
  char* ws = (char*)d_ws;

  // workspace layout (92.3 MB peak, overlaid):
  u16* xb   = (u16*)(ws);                          // [4096][2048] bf16, 16 MB
  u16* wqT  = (u16*)(ws + (size_t)16777216);       // [6144][2048] bf16, 24 MB
  u16* qkvb = (u16*)(ws + (size_t)41943040);       // [4096][6144] bf16, 48 MB
  u16* vtb  = (u16*)(ws + (size_t)16777216);       // [32][128][2048] bf16 (reuses wqT)
  u16* wdT  = (u16*)(ws + (size_t)33554432);       // [2048][2048] bf16 (reuses wqT tail)
  u16* ctxb = (u16*)(ws);                          // [4096][2048] bf16 (reuses xb)

  k_cast_bf16<<<8192, 256, 0, stream>>>(x, xb, 2097152);
  k_transpose_cast<<<dim3(192, 64), dim3(32, 8), 0, stream>>>(wq, wqT, 2048, 6144);
  k_gemm_bt<true><<<dim3(48, 32), 256, 0, stream>>>(xb, wqT, bq, (void*)qkvb, 4096, 6144, 2048);
  k_extract_vt<<<dim3(4, 64, 32), dim3(32, 8), 0, stream>>>(qkvb, vtb);
  k_transpose_cast<<<dim3(64, 64), dim3(32, 8), 0, stream>>>(wd, wdT, 2048, 2048);
  k_attn<<<dim3(32, 16), 256, 0, stream>>>(qkvb, vtb, am, ctxb);
  k_gemm_bt<false><<<dim3(16, 32), 256, 0, stream>>>(ctxb, wdT, bd, (void*)out, 4096, 2048, 2048);
}

// Round 5
// 312.709 us; speedup vs baseline: 1.2845x; 1.1162x over previous
//
#include <hip/hip_runtime.h>
#include <hip/hip_bf16.h>

typedef __bf16 bf16x8 __attribute__((ext_vector_type(8)));
typedef float f32x4 __attribute__((ext_vector_type(4)));
typedef float f32x16 __attribute__((ext_vector_type(16)));
typedef unsigned short u16;

#define S_ 2048
#define D_ 2048
#define H_ 16
#define HD_ 128
#define SCALE_ 0.08838834764831845f   // 1/sqrt(128)

__device__ __forceinline__ u16 f2bf(float f) {
  unsigned u = __builtin_bit_cast(unsigned, f);
  u += 0x7fffu + ((u >> 16) & 1u);    // RNE
  return (u16)(u >> 16);
}

__device__ __forceinline__ void gload16(void* lds, const void* g) {
  __builtin_amdgcn_global_load_lds((const __attribute__((address_space(1))) void*)g,
                                   (__attribute__((address_space(3))) void*)lds, 16, 0, 0);
}

__device__ __forceinline__ f32x4 mfma16(bf16x8 a, bf16x8 b, f32x4 c) {
  return __builtin_amdgcn_mfma_f32_16x16x32_bf16(a, b, c, 0, 0, 0);
}
__device__ __forceinline__ f32x16 mfma32(bf16x8 a, bf16x8 b, f32x16 c) {
  return __builtin_amdgcn_mfma_f32_32x32x16_bf16(a, b, c, 0, 0, 0);
}

__device__ __forceinline__ unsigned cvt_pk_bf16(float lo, float hi) {
  unsigned r;
  asm("v_cvt_pk_bf16_f32 %0, %1, %2" : "=v"(r) : "v"(lo), "v"(hi));
  return r;
}

// ---------------- cast f32 -> bf16, vectorized ----------------
__global__ void k_cast_bf16(const float* __restrict__ in, u16* __restrict__ out, int n4) {
  int i = blockIdx.x * blockDim.x + threadIdx.x;
  if (i < n4) {
    float4 v = ((const float4*)in)[i];
    ushort4 o;
    o.x = f2bf(v.x); o.y = f2bf(v.y); o.z = f2bf(v.z); o.w = f2bf(v.w);
    ((ushort4*)out)[i] = o;
  }
}

// ------------- transpose + cast: in[rows][cols] f32 -> out[cols][rows] bf16 -------------
__global__ void k_transpose_cast(const float* __restrict__ in, u16* __restrict__ out,
                                 int rows, int cols) {
  __shared__ u16 tile[32][33];
  int c0 = blockIdx.x * 32, r0 = blockIdx.y * 32;
  int tx = threadIdx.x, ty = threadIdx.y;   // (32,8)
#pragma unroll
  for (int i = 0; i < 4; i++) {
    int r = r0 + ty + i * 8;
    tile[ty + i * 8][tx] = f2bf(in[(long)r * cols + c0 + tx]);
  }
  __syncthreads();
#pragma unroll
  for (int i = 0; i < 4; i++) {
    int c = c0 + ty + i * 8;
    out[(long)c * rows + r0 + tx] = tile[tx][ty + i * 8];
  }
}

// ------------- extract V^T: qkv[4096][6144] -> vt[32][128][2048] -------------
__global__ void k_extract_vt(const u16* __restrict__ qkv, u16* __restrict__ vt) {
  __shared__ u16 tile[32][33];
  int bh = blockIdx.z, b = bh >> 4, h = bh & 15;
  int d0 = blockIdx.x * 32, s0 = blockIdx.y * 32;
  int tx = threadIdx.x, ty = threadIdx.y;
#pragma unroll
  for (int i = 0; i < 4; i++) {
    int s = s0 + ty + i * 8;
    tile[ty + i * 8][tx] = qkv[(long)(b * S_ + s) * 6144 + h * 384 + 256 + d0 + tx];
  }
  __syncthreads();
#pragma unroll
  for (int i = 0; i < 4; i++) {
    int d = d0 + ty + i * 8;
    vt[((long)bh * HD_ + d) * S_ + s0 + tx] = tile[tx][ty + i * 8];
  }
}

// ------------- pipelined GEMM: C[M][N] = A[M][K]*Bt[N][K]^T + bias -------------
// 256(M)x128(N) tile, BK=64, 512 thr = 8 waves (4m x 2n), per-wave 64x64.
// LDS 96 KB: A 2x[256][64], B 2x[128][64], rows 128 B, chunk^(row&7) swizzle.
// 2 phases/K-tile, counted vmcnt(4) (never 0 in steady state):
//   ph1(t): ds A-frags + B(n01) | stage B(t+1) | bar | lgkm0 | 16 MFMA | bar
//   ph2(t): ds B(n23)           | stage A(t+2) | bar | vmcnt(4)+lgkm0 | 16 MFMA | bar
// A(t+2) may reuse buf(t)'s A-space: dead after ph1's lgkmcnt(0).
template <bool BF16OUT>
__global__ __launch_bounds__(512) void k_gemm2(const u16* __restrict__ A,
                                               const u16* __restrict__ Bt,
                                               const float* __restrict__ bias,
                                               void* __restrict__ Cv,
                                               int M, int N, int K, int NTM) {
  __shared__ __align__(16) u16 lA[2][256 * 64];
  __shared__ __align__(16) u16 lB[2][128 * 64];
  const int tid = threadIdx.x, w = tid >> 6, l = tid & 63;
  const int wr = w >> 1, wc = w & 1, lr = l & 15, lg = l >> 4;
  const int nwg = NTM * (N >> 7);
  const int per = nwg >> 3;                     // nwg % 8 == 0 by construction
  const int wgid = ((int)blockIdx.x & 7) * per + ((int)blockIdx.x >> 3);
  const int tm = (wgid % NTM) << 8;
  const int tn = (wgid / NTM) << 7;
  const int NT = K >> 6;

  f32x4 acc[4][4];
#pragma unroll
  for (int m = 0; m < 4; m++)
#pragma unroll
    for (int n = 0; n < 4; n++) acc[m][n] = {0.f, 0.f, 0.f, 0.f};

  auto stageA = [&](int buf, int kt) {
#pragma unroll
    for (int i = 0; i < 4; i++) {
      int base = i * 512 + w * 64;              // wave-uniform chunk base
      int fl = base + l, r = fl >> 3, cg = (fl & 7) ^ (r & 7);
      gload16(&lA[buf][base * 8], &A[(long)(tm + r) * K + kt * 64 + cg * 8]);
    }
  };
  auto stageB = [&](int buf, int kt) {
#pragma unroll
    for (int i = 0; i < 2; i++) {
      int base = i * 512 + w * 64;
      int fl = base + l, r = fl >> 3, cg = (fl & 7) ^ (r & 7);
      gload16(&lB[buf][base * 8], &Bt[(long)(tn + r) * K + kt * 64 + cg * 8]);
    }
  };

  // prologue: tile0 (A+B) + A(1); counted wait leaves A(1) in flight
  stageA(0, 0);
  stageB(0, 0);
  if (NT > 1) stageA(1, 1);
  asm volatile("s_waitcnt vmcnt(4)" ::: "memory");
  __builtin_amdgcn_s_barrier();

  for (int kt = 0; kt < NT; ++kt) {
    const int b = kt & 1;
    bf16x8 af[4][2], bfr[2][2];
    // ---- phase 1: n-frags 0,1 ----
#pragma unroll
    for (int m = 0; m < 4; m++)
#pragma unroll
      for (int k = 0; k < 2; k++) {
        int r = wr * 64 + m * 16 + lr;
        af[m][k] = *(const bf16x8*)&lA[b][r * 64 + ((((k << 2) + lg) ^ (r & 7)) << 3)];
      }
#pragma unroll
    for (int n = 0; n < 2; n++)
#pragma unroll
      for (int k = 0; k < 2; k++) {
        int r = wc * 64 + n * 16 + lr;
        bfr[n][k] = *(const bf16x8*)&lB[b][r * 64 + ((((k << 2) + lg) ^ (r & 7)) << 3)];
      }
    if (kt + 1 < NT) stageB(b ^ 1, kt + 1);
    __builtin_amdgcn_s_barrier();
    asm volatile("s_waitcnt lgkmcnt(0)" ::: "memory");
    __builtin_amdgcn_sched_barrier(0);
    __builtin_amdgcn_s_setprio(1);
#pragma unroll
    for (int m = 0; m < 4; m++)
#pragma unroll
      for (int n = 0; n < 2; n++)
#pragma unroll
        for (int k = 0; k < 2; k++)
          acc[m][n] = mfma16(af[m][k], bfr[n][k], acc[m][n]);
    __builtin_amdgcn_s_setprio(0);
    __builtin_amdgcn_s_barrier();

    // ---- phase 2: n-frags 2,3 ----
#pragma unroll
    for (int n = 0; n < 2; n++)
#pragma unroll
      for (int k = 0; k < 2; k++) {
        int r = wc * 64 + (n + 2) * 16 + lr;
        bfr[n][k] = *(const bf16x8*)&lB[b][r * 64 + ((((k << 2) + lg) ^ (r & 7)) << 3)];
      }
    if (kt + 2 < NT) stageA(b, kt + 2);
    __builtin_amdgcn_s_barrier();
    if (kt + 2 < NT)
      asm volatile("s_waitcnt vmcnt(4) lgkmcnt(0)" ::: "memory");
    else
      asm volatile("s_waitcnt vmcnt(0) lgkmcnt(0)" ::: "memory");
    __builtin_amdgcn_sched_barrier(0);
    __builtin_amdgcn_s_setprio(1);
#pragma unroll
    for (int m = 0; m < 4; m++)
#pragma unroll
      for (int n = 0; n < 2; n++)
#pragma unroll
        for (int k = 0; k < 2; k++)
          acc[m][n + 2] = mfma16(af[m][k], bfr[n][k], acc[m][n + 2]);
    __builtin_amdgcn_s_setprio(0);
    __builtin_amdgcn_s_barrier();
  }

  // epilogue
#pragma unroll
  for (int n = 0; n < 4; n++) {
    int col = tn + wc * 64 + n * 16 + lr;
    float bv = bias[col];
#pragma unroll
    for (int m = 0; m < 4; m++) {
      int row0 = tm + wr * 64 + m * 16 + lg * 4;
#pragma unroll
      for (int j = 0; j < 4; j++) {
        float v = acc[m][n][j] + bv;
        if constexpr (BF16OUT)
          ((u16*)Cv)[(long)(row0 + j) * N + col] = f2bf(v);
        else
          ((float*)Cv)[(long)(row0 + j) * N + col] = v;
      }
    }
  }
}

// ------------- causal flash attention, 32x32 swapped-MFMA form -------------
__global__ __launch_bounds__(256) void k_attn(const u16* __restrict__ qkv,
                                              const u16* __restrict__ vt,
                                              const float* __restrict__ amask,
                                              u16* __restrict__ ctx) {
  __shared__ u16 lK[2][64 * 128];    // [key][d], 16B-chunk ^(key&7) swizzle
  __shared__ u16 lV[2][128 * 64];    // [d][key], 16B-chunk ^(d&7) swizzle
  __shared__ float lAM[S_];          // amask row for this b
  const int bh = blockIdx.x, b = bh >> 4, h = bh & 15;
  const int c = blockIdx.y;
  const int tid = threadIdx.x, w = tid >> 6, l = tid & 63;
  const int lr5 = l & 31, hi = l >> 5;
  const int qrow0 = (w < 2) ? (c * 64 + w * 32) : ((31 - c) * 64 + (w - 2) * 32);
  const int ntiles = 32 - c;

  for (int i = tid; i < S_; i += 256) lAM[i] = amask[b * S_ + i];

  bf16x8 qf[8];
#pragma unroll
  for (int ks = 0; ks < 8; ks++)
    qf[ks] = *(const bf16x8*)&qkv[(long)(b * S_ + qrow0 + lr5) * 6144 +
                                  h * 384 + ks * 16 + hi * 8];

  f32x16 aO[4];
#pragma unroll
  for (int db = 0; db < 4; db++)
#pragma unroll
    for (int r = 0; r < 16; r++) aO[db][r] = 0.f;
  float mrun = -3.0e38f, lrun = 0.f;

  auto stage = [&](int buf, int t) {
#pragma unroll
    for (int i = 0; i < 4; i++) {
      int base = i * 256 + w * 64;
      int f = base + l;
      int r = f >> 4, cg = (f & 15) ^ (r & 7);
      gload16(&lK[buf][base * 8],
              &qkv[(long)(b * S_ + t * 64 + r) * 6144 + h * 384 + 128 + cg * 8]);
    }
#pragma unroll
    for (int i = 0; i < 4; i++) {
      int base = i * 256 + w * 64;
      int f = base + l;
      int r = f >> 3, cg = (f & 7) ^ (r & 7);
      gload16(&lV[buf][base * 8], &vt[((long)bh * HD_ + r) * S_ + t * 64 + cg * 8]);
    }
  };

  stage(0, 0);
  __syncthreads();

  for (int t = 0; t < ntiles; ++t) {
    const int cur = t & 1;
    if (t + 1 < ntiles) stage(cur ^ 1, t + 1);

    if (t * 64 <= qrow0 + 31) {
      const int t64 = t * 64;
      const int qr = qrow0 + lr5;
      f32x16 aS0, aS1;
#pragma unroll
      for (int r = 0; r < 16; r++) { aS0[r] = 0.f; aS1[r] = 0.f; }
      __builtin_amdgcn_s_setprio(1);
#pragma unroll
      for (int ks = 0; ks < 8; ks++) {
        int cg = 2 * ks + hi;
        bf16x8 kf0 = *(const bf16x8*)&lK[cur][lr5 * 128 + ((cg ^ (lr5 & 7)) << 3)];
        bf16x8 kf1 = *(const bf16x8*)&lK[cur][(32 + lr5) * 128 + ((cg ^ (lr5 & 7)) << 3)];
        aS0 = mfma32(kf0, qf[ks], aS0);
        aS1 = mfma32(kf1, qf[ks], aS1);
      }
      __builtin_amdgcn_s_setprio(0);

      float v0[16], v1[16];
      const bool needmask = (t64 + 63 > qrow0);
#pragma unroll
      for (int rg = 0; rg < 4; rg++) {
        f32x4 am0 = *(const f32x4*)&lAM[t64 + rg * 8 + hi * 4];
        f32x4 am1 = *(const f32x4*)&lAM[t64 + 32 + rg * 8 + hi * 4];
#pragma unroll
        for (int j = 0; j < 4; j++) {
          v0[rg * 4 + j] = fmaf(aS0[rg * 4 + j], SCALE_, am0[j]);
          v1[rg * 4 + j] = fmaf(aS1[rg * 4 + j], SCALE_, am1[j]);
          if (needmask) {
            if (t64 + rg * 8 + 4 * hi + j > qr)      v0[rg * 4 + j] = -1e30f;
            if (t64 + 32 + rg * 8 + 4 * hi + j > qr) v1[rg * 4 + j] = -1e30f;
          }
        }
      }
      float mx = v0[0];
#pragma unroll
      for (int i = 1; i < 16; i++) mx = fmaxf(mx, v0[i]);
#pragma unroll
      for (int i = 0; i < 16; i++) mx = fmaxf(mx, v1[i]);
      mx = fmaxf(mx, __shfl_xor(mx, 32));

      if (!__all(mx <= mrun + 8.0f)) {
        float mnew = fmaxf(mrun, mx);
        float corr = __expf(mrun - mnew);
        lrun *= corr;
        mrun = mnew;
#pragma unroll
        for (int reg = 0; reg < 16; reg++) {
          float cb = __shfl(corr, (reg & 3) + 8 * (reg >> 2) + 4 * hi);
#pragma unroll
          for (int db = 0; db < 4; db++) aO[db][reg] *= cb;
        }
      }

      float p0[16], p1[16], ls = 0.f;
#pragma unroll
      for (int i = 0; i < 16; i++) { p0[i] = __expf(v0[i] - mrun); ls += p0[i]; }
#pragma unroll
      for (int i = 0; i < 16; i++) { p1[i] = __expf(v1[i] - mrun); ls += p1[i]; }
      ls += __shfl_xor(ls, 32);
      lrun += ls;

      unsigned pk0[8], pk1[8];
#pragma unroll
      for (int q = 0; q < 8; q++) {
        pk0[q] = cvt_pk_bf16(p0[2 * q], p0[2 * q + 1]);
        pk1[q] = cvt_pk_bf16(p1[2 * q], p1[2 * q + 1]);
      }
      bf16x8 pa[4];
#pragma unroll
      for (int kst = 0; kst < 4; kst++) {
        const int j4 = kst & 1;
        unsigned a0, a1, a2, a3;
        if (kst < 2) { a0 = pk0[4 * j4]; a1 = pk0[4 * j4 + 1]; a2 = pk0[4 * j4 + 2]; a3 = pk0[4 * j4 + 3]; }
        else         { a0 = pk1[4 * j4]; a1 = pk1[4 * j4 + 1]; a2 = pk1[4 * j4 + 2]; a3 = pk1[4 * j4 + 3]; }
        unsigned s0 = hi ? a0 : a2;
        unsigned s1 = hi ? a1 : a3;
        unsigned r0 = __shfl_xor(s0, 32);
        unsigned r1 = __shfl_xor(s1, 32);
        union { unsigned u[4]; bf16x8 v; } U;
        U.u[0] = hi ? r0 : a0;
        U.u[1] = hi ? r1 : a1;
        U.u[2] = hi ? a2 : r0;
        U.u[3] = hi ? a3 : r1;
        pa[kst] = U.v;
      }

      __builtin_amdgcn_s_setprio(1);
#pragma unroll
      for (int kst = 0; kst < 4; kst++) {
#pragma unroll
        for (int db = 0; db < 4; db++) {
          int d = db * 32 + lr5;
          int cg = (2 * kst + hi) ^ (d & 7);
          bf16x8 vb = *(const bf16x8*)&lV[cur][d * 64 + (cg << 3)];
          aO[db] = mfma32(pa[kst], vb, aO[db]);
        }
      }
      __builtin_amdgcn_s_setprio(0);
    }
    __syncthreads();
  }

  float inv = 1.0f / lrun;
#pragma unroll
  for (int reg = 0; reg < 16; reg++) {
    int r = (reg & 3) + 8 * (reg >> 2) + 4 * hi;
    float ib = __shfl(inv, r);
    int srow = qrow0 + r;
#pragma unroll
    for (int db = 0; db < 4; db++)
      ctx[(long)(b * S_ + srow) * D_ + h * HD_ + db * 32 + lr5] = f2bf(aO[db][reg] * ib);
  }
}

extern "C" void kernel_launch(void* const* d_in, const int* in_sizes, int n_in,
                              void* d_out, int out_size, void* d_ws, size_t ws_size,
                              hipStream_t stream) {
  const float* x  = (const float*)d_in[0];
  const float* am = (const float*)d_in[1];
  const float* wq = (const float*)d_in[2];
  const float* bq = (const float*)d_in[3];
  const float* wd = (const float*)d_in[4];
  const float* bd = (const float*)d_in[5];
  float* out = (float*)d_out;
  char* ws = (char*)d_ws;

  // workspace layout (92.3 MB peak, overlaid):
  u16* xb   = (u16*)(ws);                          // [4096][2048] bf16, 16 MB
  u16* wqT  = (u16*)(ws + (size_t)16777216);       // [6144][2048] bf16, 24 MB
  u16* qkvb = (u16*)(ws + (size_t)41943040);       // [4096][6144] bf16, 48 MB
  u16* vtb  = (u16*)(ws + (size_t)16777216);       // [32][128][2048] bf16 (reuses wqT)
  u16* wdT  = (u16*)(ws + (size_t)33554432);       // [2048][2048] bf16 (reuses wqT tail)
  u16* ctxb = (u16*)(ws);                          // [4096][2048] bf16 (reuses xb)

  k_cast_bf16<<<8192, 256, 0, stream>>>(x, xb, 2097152);
  k_transpose_cast<<<dim3(192, 64), dim3(32, 8), 0, stream>>>(wq, wqT, 2048, 6144);
  k_gemm2<true><<<768, 512, 0, stream>>>(xb, wqT, bq, (void*)qkvb, 4096, 6144, 2048, 16);
  k_extract_vt<<<dim3(4, 64, 32), dim3(32, 8), 0, stream>>>(qkvb, vtb);
  k_transpose_cast<<<dim3(64, 64), dim3(32, 8), 0, stream>>>(wd, wdT, 2048, 2048);
  k_attn<<<dim3(32, 16), 256, 0, stream>>>(qkvb, vtb, am, ctxb);
  k_gemm2<false><<<256, 512, 0, stream>>>(ctxb, wdT, bd, (void*)out, 4096, 2048, 2048, 16);
}